// Round 6
// baseline (1202.064 us; speedup 1.0000x reference)
//
#include <hip/hip_runtime.h>

// Problem constants (from reference)
#define E_EDGES 131072
#define K_NB    10
#define D_DIM   128
#define U_DIM   32
#define A_DIM   16
#define R_DIM   4

// Kernel tiling
#define EPG     4                    // edge-sides per wave pass
#define WAVES   16                   // waves per block (1024 threads)
#define BLOCK   (WAVES * 64)
#define NGROUPS ((2 * E_EDGES) / EPG)   // 65536 wave-groups
#define NBLOCKS (NGROUPS / WAVES)       // 4096 blocks

// fast 1/x (v_rcp_f32, ~1e-7 rel err)
__device__ __forceinline__ float frcp(float x) { return __builtin_amdgcn_rcpf(x); }

// fast tanh via hardware exp2: tanh(x) = (e^{2x}-1)/(e^{2x}+1), clamped so
// e^{2x} can't overflow (tanh saturates to 1.0f well before |x|=10)
__device__ __forceinline__ float fast_tanh(float x) {
    x = fminf(fmaxf(x, -10.f), 10.f);
    const float t = __expf(2.f * x);
    return (t - 1.f) * frcp(t + 1.f);
}

// Design point (R5): LDS 48KB/block -> 2 blocks/CU = 8 waves/EU; the
// compiler's preferred 64-VGPR allocation is now BOTH sufficient (no Wreg[32],
// peak live ~50) AND useful (8 waves/EU actually reachable). M streams from
// L2 (64KB, permanently hot, coalesced float2, no deps -> latency hidden).
__global__ __launch_bounds__(BLOCK)
void gatne_fused(const int*   __restrict__ edge_index,  // [2,E]
                 const float* __restrict__ edge_attr,   // [E,R]
                 const int*   __restrict__ nbr,         // [2,E,K]
                 const float* __restrict__ emb,         // [N,D]
                 const float* __restrict__ u,           // [N,R,U] (=[N,128])
                 const float* __restrict__ Wt,          // [R,U,A]
                 const float* __restrict__ wt,          // [R,A]
                 const float* __restrict__ Mt,          // [R,U,D] (=[128,128])
                 float*       __restrict__ out)         // [2,E,D]
{
    __shared__ float W_lds[U_DIM * 64];                 // 8 KB, [u][rl*16+al]
    __shared__ float ur_lds[WAVES][D_DIM];              // 8 KB  (per-wave u_r)
    __shared__ float coef_lds[WAVES][EPG][D_DIM];       // 32 KB (per-wave coef)

    const int tid = threadIdx.x;

    // ---- stage W into LDS (one barrier for the whole kernel) ----
    // W relayout: W_lds[u*64 + (rl*16+al)] = W[rl][u][al]; lane reads column
    // `lane` (bank = lane%32 -> 2-way aliasing = free).
    #pragma unroll
    for (int j = 0; j < (U_DIM * 64) / BLOCK; ++j) {
        const int idx = j * BLOCK + tid;
        const int uu  = idx >> 6;
        const int ln  = idx & 63;
        W_lds[idx] = Wt[((ln >> 4) * U_DIM + uu) * A_DIM + (ln & 15)];
    }
    __syncthreads();

    const int wave = tid >> 6;
    const int lane = tid & 63;
    const int grp  = blockIdx.x * WAVES + wave;   // one group of EPG edge-sides
    const int es0  = grp * EPG;                   // first edge-side id
    const int side = es0 / E_EDGES;               // uniform within group
    const int i0   = es0 - side * E_EDGES;        // edge id of first

    // lane -> (r'=rl, a=al) mapping for the attention score phase
    const int rl = lane >> 4;
    const int al = lane & 15;

    const float wreg0 = wt[0 * A_DIM + al];
    const float wreg1 = wt[1 * A_DIM + al];
    const float wreg2 = wt[2 * A_DIM + al];
    const float wreg3 = wt[3 * A_DIM + al];

    // cooperative index / attr loads (broadcast later via shfl/readlane)
    int idxA = 0;
    if (lane < EPG * K_NB) idxA = nbr[es0 * K_NB + lane];          // 40 ints
    int entv = 0;
    if (lane < EPG)        entv = edge_index[es0 + lane];          // 4 ints
    float attrv = 0.f;
    if (lane < EPG * R_DIM) attrv = edge_attr[i0 * R_DIM + lane];  // 16 floats

    float* urp = ur_lds[wave];
    float* cfp = &coef_lds[wave][0][0];

    // ---------------- phase 1: ALL gathers up front (max MLP) ----------------
    float2 b2[EPG];
    float2 s[EPG];
    #pragma unroll
    for (int e = 0; e < EPG; ++e) {
        const int ent = __shfl(entv, e);
        b2[e] = *reinterpret_cast<const float2*>(&emb[ent * D_DIM + 2 * lane]);
        s[e] = make_float2(0.f, 0.f);
    }
    #pragma unroll
    for (int e = 0; e < EPG; ++e) {
        #pragma unroll
        for (int k = 0; k < K_NB; ++k) {
            const int node = __shfl(idxA, e * K_NB + k);   // uniform -> readlane
            const float2 v =
                *reinterpret_cast<const float2*>(&u[node * D_DIM + 2 * lane]);
            s[e].x += v.x; s[e].y += v.y;
        }
    }

    // ---------------- phase 2: per-edge attention + coef ----------------
    #pragma unroll
    for (int e = 0; e < EPG; ++e) {
        const float at0 = __shfl(attrv, e * 4 + 0);
        const float at1 = __shfl(attrv, e * 4 + 1);
        const float at2 = __shfl(attrv, e * 4 + 2);
        const float at3 = __shfl(attrv, e * 4 + 3);
        // this lane's attr[rl] (rl == (2*lane)>>5 too, reused for coef)
        const float atm = (rl == 0) ? at0 : (rl == 1) ? at1 : (rl == 2) ? at2 : at3;

        *reinterpret_cast<float2*>(&urp[2 * lane]) =
            make_float2(s[e].x * 0.1f, s[e].y * 0.1f);   // mean over K=10
        // wave-private LDS: in-order DS pipe makes this visible to all lanes
        // without a barrier (single-wave producer/consumer).

        // w_r[al] = sum_r' attr[r'] * w[r',al]
        const float wr = at0 * wreg0 + at1 * wreg1 + at2 * wreg2 + at3 * wreg3;

        // scores: g[r] = sum_u u_r[r,u] * W[rl,u,al];  h[r,al] = sum_rl attr*g
        // W read from LDS (column `lane`, conflict-free) -> no Wreg[32] hog.
        float sc[R_DIM];
        #pragma unroll
        for (int r = 0; r < R_DIM; ++r) {
            float g = 0.f;
            #pragma unroll
            for (int u4 = 0; u4 < U_DIM / 4; ++u4) {
                const float4 uv =
                    *reinterpret_cast<const float4*>(&urp[r * U_DIM + u4 * 4]);
                g += uv.x * W_lds[(u4 * 4 + 0) * 64 + lane];
                g += uv.y * W_lds[(u4 * 4 + 1) * 64 + lane];
                g += uv.z * W_lds[(u4 * 4 + 2) * 64 + lane];
                g += uv.w * W_lds[(u4 * 4 + 3) * 64 + lane];
            }
            float v0 = atm * g;
            v0 += __shfl_xor(v0, 16);           // reduce over r' groups
            v0 += __shfl_xor(v0, 32);
            float t = fast_tanh(v0) * wr;       // tanh(h[r,al]) * w_r[al]
            t += __shfl_xor(t, 1);              // reduce over a
            t += __shfl_xor(t, 2);
            t += __shfl_xor(t, 4);
            t += __shfl_xor(t, 8);
            sc[r] = t;                          // score[r], replicated all lanes
        }

        // softmax over R=4 (replicated per-lane, trivial)
        const float mx  = fmaxf(fmaxf(sc[0], sc[1]), fmaxf(sc[2], sc[3]));
        const float ex0 = __expf(sc[0] - mx), ex1 = __expf(sc[1] - mx);
        const float ex2 = __expf(sc[2] - mx), ex3 = __expf(sc[3] - mx);
        const float inv = frcp(ex0 + ex1 + ex2 + ex3);
        const float a0 = ex0 * inv, a1 = ex1 * inv, a2 = ex2 * inv, a3 = ex3 * inv;

        // coef[ru] = attr[r] * v[u], v[u] = sum_r att[r]*u_r[r,u]
        // lane owns ru = 2*lane, 2*lane+1  (r = lane>>4 = rl)
        const int ub = (2 * lane) & 31;
        const float vA = a0 * urp[0 * U_DIM + ub]     + a1 * urp[1 * U_DIM + ub] +
                         a2 * urp[2 * U_DIM + ub]     + a3 * urp[3 * U_DIM + ub];
        const float vB = a0 * urp[0 * U_DIM + ub + 1] + a1 * urp[1 * U_DIM + ub + 1] +
                         a2 * urp[2 * U_DIM + ub + 1] + a3 * urp[3 * U_DIM + ub + 1];
        *reinterpret_cast<float2*>(&cfp[e * D_DIM + 2 * lane]) =
            make_float2(atm * vA, atm * vB);
    }

    // ------- joint matvec: out_d = sum_ru coef[ru] * M[ru,d], M from L2 ------
    float2 acc[EPG];
    #pragma unroll
    for (int e = 0; e < EPG; ++e) { acc[e].x = 0.f; acc[e].y = 0.f; }

    for (int c = 0; c < (R_DIM * U_DIM) / 4; ++c) {    // 32 chunks of 4 ru
        float4 cf4[EPG];                               // uniform (broadcast) reads
        #pragma unroll
        for (int e = 0; e < EPG; ++e)
            cf4[e] = *reinterpret_cast<const float4*>(&cfp[e * D_DIM + c * 4]);
        #pragma unroll
        for (int jj = 0; jj < 4; ++jj) {
            const float2 m2 = *reinterpret_cast<const float2*>(
                &Mt[(c * 4 + jj) * D_DIM + 2 * lane]);   // coalesced, L2-hot
            #pragma unroll
            for (int e = 0; e < EPG; ++e) {
                const float cv = (jj == 0) ? cf4[e].x : (jj == 1) ? cf4[e].y
                               : (jj == 2) ? cf4[e].z : cf4[e].w;
                acc[e].x += cv * m2.x;
                acc[e].y += cv * m2.y;
            }
        }
    }

    // ---------------- epilogue: + emb, L2 normalize, store -------------------
    #pragma unroll
    for (int e = 0; e < EPG; ++e) {
        const float ox = b2[e].x + acc[e].x;
        const float oy = b2[e].y + acc[e].y;
        float ss = ox * ox + oy * oy;
        ss += __shfl_xor(ss, 1);
        ss += __shfl_xor(ss, 2);
        ss += __shfl_xor(ss, 4);
        ss += __shfl_xor(ss, 8);
        ss += __shfl_xor(ss, 16);
        ss += __shfl_xor(ss, 32);
        const float scale = frcp(fmaxf(sqrtf(ss), 1e-12f));
        *reinterpret_cast<float2*>(&out[(es0 + e) * D_DIM + 2 * lane]) =
            make_float2(ox * scale, oy * scale);
    }
}

extern "C" void kernel_launch(void* const* d_in, const int* in_sizes, int n_in,
                              void* d_out, int out_size, void* d_ws, size_t ws_size,
                              hipStream_t stream)
{
    const int*   edge_index = (const int*)  d_in[0];   // [2,E]
    const float* edge_attr  = (const float*)d_in[1];   // [E,R]
    const int*   nbr        = (const int*)  d_in[2];   // [2,E,K]
    const float* emb        = (const float*)d_in[3];   // [N,D]
    const float* u          = (const float*)d_in[4];   // [N,R,U]
    const float* Wt         = (const float*)d_in[5];   // [R,U,A]
    const float* wt         = (const float*)d_in[6];   // [R,A]
    const float* Mt         = (const float*)d_in[7];   // [R,U,D]
    float*       out        = (float*)d_out;           // [2,E,D]

    gatne_fused<<<dim3(NBLOCKS), dim3(BLOCK), 0, stream>>>(
        edge_index, edge_attr, nbr, emb, u, Wt, wt, Mt, out);
}

// Round 8
// 693.288 us; speedup vs baseline: 1.7339x; 1.7339x over previous
//
#include <hip/hip_runtime.h>

// Problem constants (from reference)
#define E_EDGES 131072
#define K_NB    10
#define D_DIM   128
#define U_DIM   32
#define A_DIM   16
#define R_DIM   4

// Kernel tiling (R7): back to 512-thread blocks — the ONLY regime where the
// allocator gave us 128 VGPRs with zero spill (R1). 1024-thread blocks pick
// 64 VGPRs and spill 0.3-1.4 GB no matter what we do (R3/R4/R6).
#define EPG     4                    // edge-sides per wave pass
#define WAVES   8                    // waves per block (512 threads)
#define BLOCK   (WAVES * 64)
#define NGROUPS ((2 * E_EDGES) / EPG)   // 65536 wave-groups
#define NBLOCKS (NGROUPS / WAVES)       // 8192 blocks

// fast 1/x (v_rcp_f32, ~1e-7 rel err)
__device__ __forceinline__ float frcp(float x) { return __builtin_amdgcn_rcpf(x); }

// fast tanh via hardware exp2 (validated R3/R4/R6: absmax 2^-10, passes)
__device__ __forceinline__ float fast_tanh(float x) {
    x = fminf(fmaxf(x, -10.f), 10.f);
    const float t = __expf(2.f * x);
    return (t - 1.f) * frcp(t + 1.f);
}

// LDS 28KB/block -> 2 blocks/CU at 128 VGPR = 16 waves/CU (2x R1).
// launch_bounds(512,4): min 4 waves/EU -> VGPR cap 512/4 = 128 exactly.
__global__ __launch_bounds__(BLOCK, 4)
void gatne_fused(const int*   __restrict__ edge_index,  // [2,E]
                 const float* __restrict__ edge_attr,   // [E,R]
                 const int*   __restrict__ nbr,         // [2,E,K]
                 const float* __restrict__ emb,         // [N,D]
                 const float* __restrict__ u,           // [N,R,U] (=[N,128])
                 const float* __restrict__ Wt,          // [R,U,A]
                 const float* __restrict__ wt,          // [R,A]
                 const float* __restrict__ Mt,          // [R,U,D] (=[128,128])
                 float*       __restrict__ out)         // [2,E,D]
{
    __shared__ float W_lds[U_DIM * 64];                 // 8 KB, [u][rl*16+al]
    __shared__ float ur_lds[WAVES][D_DIM];              // 4 KB  (per-wave u_r)
    __shared__ float coef_lds[WAVES][EPG][D_DIM];       // 16 KB (per-wave coef)

    const int tid = threadIdx.x;

    // ---- stage W into LDS (one barrier for the whole kernel) ----
    // W_lds[u*64 + (rl*16+al)] = W[rl][u][al]; lane reads column `lane`
    // (bank = lane%32 -> 2-way aliasing = free, m136).
    #pragma unroll
    for (int j = 0; j < (U_DIM * 64) / BLOCK; ++j) {
        const int idx = j * BLOCK + tid;
        const int uu  = idx >> 6;
        const int ln  = idx & 63;
        W_lds[idx] = Wt[((ln >> 4) * U_DIM + uu) * A_DIM + (ln & 15)];
    }
    __syncthreads();

    const int wave = tid >> 6;
    const int lane = tid & 63;
    const int grp  = blockIdx.x * WAVES + wave;   // one group of EPG edge-sides
    const int es0  = grp * EPG;                   // first edge-side id
    const int side = es0 / E_EDGES;               // uniform within group
    const int i0   = es0 - side * E_EDGES;        // edge id of first

    // lane -> (r'=rl, a=al) mapping for the attention score phase
    const int rl = lane >> 4;
    const int al = lane & 15;

    const float wreg0 = wt[0 * A_DIM + al];
    const float wreg1 = wt[1 * A_DIM + al];
    const float wreg2 = wt[2 * A_DIM + al];
    const float wreg3 = wt[3 * A_DIM + al];

    // cooperative index / attr loads (broadcast later via shfl/readlane)
    int idxA = 0;
    if (lane < EPG * K_NB) idxA = nbr[es0 * K_NB + lane];          // 40 ints
    int entv = 0;
    if (lane < EPG)        entv = edge_index[es0 + lane];          // 4 ints
    float attrv = 0.f;
    if (lane < EPG * R_DIM) attrv = edge_attr[i0 * R_DIM + lane];  // 16 floats

    float* urp = ur_lds[wave];
    float* cfp = &coef_lds[wave][0][0];

    // ---------------- phase 1: ALL gathers up front (max MLP) ----------------
    float2 b2[EPG];
    float2 s[EPG];
    #pragma unroll
    for (int e = 0; e < EPG; ++e) {
        const int ent = __shfl(entv, e);
        b2[e] = *reinterpret_cast<const float2*>(&emb[ent * D_DIM + 2 * lane]);
        s[e] = make_float2(0.f, 0.f);
    }
    #pragma unroll
    for (int e = 0; e < EPG; ++e) {
        #pragma unroll
        for (int k = 0; k < K_NB; ++k) {
            const int node = __shfl(idxA, e * K_NB + k);   // uniform -> readlane
            const float2 v =
                *reinterpret_cast<const float2*>(&u[node * D_DIM + 2 * lane]);
            s[e].x += v.x; s[e].y += v.y;
        }
    }

    // ---------------- phase 2: per-edge attention + coef ----------------
    #pragma unroll
    for (int e = 0; e < EPG; ++e) {
        const float at0 = __shfl(attrv, e * 4 + 0);
        const float at1 = __shfl(attrv, e * 4 + 1);
        const float at2 = __shfl(attrv, e * 4 + 2);
        const float at3 = __shfl(attrv, e * 4 + 3);
        const float atm = (rl == 0) ? at0 : (rl == 1) ? at1 : (rl == 2) ? at2 : at3;

        *reinterpret_cast<float2*>(&urp[2 * lane]) =
            make_float2(s[e].x * 0.1f, s[e].y * 0.1f);   // mean over K=10
        // wave-private LDS: in-order DS pipe, single-wave producer/consumer.

        // w_r[al] = sum_r' attr[r'] * w[r',al]
        const float wr = at0 * wreg0 + at1 * wreg1 + at2 * wreg2 + at3 * wreg3;

        // scores: g[r] = sum_u u_r[r,u] * W[rl,u,al];  h[r,al] = sum_rl attr*g
        float sc[R_DIM];
        #pragma unroll
        for (int r = 0; r < R_DIM; ++r) {
            float g = 0.f;
            #pragma unroll
            for (int u4 = 0; u4 < U_DIM / 4; ++u4) {
                const float4 uv =
                    *reinterpret_cast<const float4*>(&urp[r * U_DIM + u4 * 4]);
                g += uv.x * W_lds[(u4 * 4 + 0) * 64 + lane];
                g += uv.y * W_lds[(u4 * 4 + 1) * 64 + lane];
                g += uv.z * W_lds[(u4 * 4 + 2) * 64 + lane];
                g += uv.w * W_lds[(u4 * 4 + 3) * 64 + lane];
            }
            float v0 = atm * g;
            v0 += __shfl_xor(v0, 16);           // reduce over r' groups
            v0 += __shfl_xor(v0, 32);
            float t = fast_tanh(v0) * wr;       // tanh(h[r,al]) * w_r[al]
            t += __shfl_xor(t, 1);              // reduce over a
            t += __shfl_xor(t, 2);
            t += __shfl_xor(t, 4);
            t += __shfl_xor(t, 8);
            sc[r] = t;                          // score[r], replicated all lanes
        }

        // softmax over R=4 (replicated per-lane, trivial)
        const float mx  = fmaxf(fmaxf(sc[0], sc[1]), fmaxf(sc[2], sc[3]));
        const float ex0 = __expf(sc[0] - mx), ex1 = __expf(sc[1] - mx);
        const float ex2 = __expf(sc[2] - mx), ex3 = __expf(sc[3] - mx);
        const float inv = frcp(ex0 + ex1 + ex2 + ex3);
        const float a0 = ex0 * inv, a1 = ex1 * inv, a2 = ex2 * inv, a3 = ex3 * inv;

        // coef[ru] = attr[r] * v[u], v[u] = sum_r att[r]*u_r[r,u]
        const int ub = (2 * lane) & 31;
        const float vA = a0 * urp[0 * U_DIM + ub]     + a1 * urp[1 * U_DIM + ub] +
                         a2 * urp[2 * U_DIM + ub]     + a3 * urp[3 * U_DIM + ub];
        const float vB = a0 * urp[0 * U_DIM + ub + 1] + a1 * urp[1 * U_DIM + ub + 1] +
                         a2 * urp[2 * U_DIM + ub + 1] + a3 * urp[3 * U_DIM + ub + 1];
        *reinterpret_cast<float2*>(&cfp[e * D_DIM + 2 * lane]) =
            make_float2(atm * vA, atm * vB);
    }

    // ------- joint matvec: out_d = sum_ru coef[ru] * M[ru,d], M from L2 ------
    // R6 lesson: an uncontrolled global-M loop made the compiler batch loads
    // -> 1.4GB spill. Control it: #pragma unroll 1 + manual A/B prefetch with
    // STATIC buffer names (rule #20), peak live ~60 regs.
    float2 acc[EPG];
    #pragma unroll
    for (int e = 0; e < EPG; ++e) { acc[e].x = 0.f; acc[e].y = 0.f; }

    const float2* mp = reinterpret_cast<const float2*>(&Mt[2 * lane]);
    float2 mA0, mA1, mA2, mA3, mB0, mB1, mB2, mB3;
    mA0 = mp[0 * 64]; mA1 = mp[1 * 64]; mA2 = mp[2 * 64]; mA3 = mp[3 * 64];

    #pragma unroll 1
    for (int c = 0; c < 32; c += 2) {
        // prefetch chunk c+1 into B while computing c from A
        {
            const float2* q = mp + (c + 1) * 4 * 64;
            mB0 = q[0 * 64]; mB1 = q[1 * 64]; mB2 = q[2 * 64]; mB3 = q[3 * 64];
        }
        {
            float4 cf4[EPG];
            #pragma unroll
            for (int e = 0; e < EPG; ++e)
                cf4[e] = *reinterpret_cast<const float4*>(&cfp[e * D_DIM + c * 4]);
            #pragma unroll
            for (int e = 0; e < EPG; ++e) {
                acc[e].x += cf4[e].x * mA0.x; acc[e].y += cf4[e].x * mA0.y;
                acc[e].x += cf4[e].y * mA1.x; acc[e].y += cf4[e].y * mA1.y;
                acc[e].x += cf4[e].z * mA2.x; acc[e].y += cf4[e].z * mA2.y;
                acc[e].x += cf4[e].w * mA3.x; acc[e].y += cf4[e].w * mA3.y;
            }
        }
        // prefetch chunk c+2 into A while computing c+1 from B
        if (c + 2 < 32) {
            const float2* q = mp + (c + 2) * 4 * 64;
            mA0 = q[0 * 64]; mA1 = q[1 * 64]; mA2 = q[2 * 64]; mA3 = q[3 * 64];
        }
        {
            float4 cf4[EPG];
            #pragma unroll
            for (int e = 0; e < EPG; ++e)
                cf4[e] = *reinterpret_cast<const float4*>(&cfp[e * D_DIM + (c + 1) * 4]);
            #pragma unroll
            for (int e = 0; e < EPG; ++e) {
                acc[e].x += cf4[e].x * mB0.x; acc[e].y += cf4[e].x * mB0.y;
                acc[e].x += cf4[e].y * mB1.x; acc[e].y += cf4[e].y * mB1.y;
                acc[e].x += cf4[e].z * mB2.x; acc[e].y += cf4[e].z * mB2.y;
                acc[e].x += cf4[e].w * mB3.x; acc[e].y += cf4[e].w * mB3.y;
            }
        }
    }

    // ---------------- epilogue: + emb, L2 normalize, store -------------------
    #pragma unroll
    for (int e = 0; e < EPG; ++e) {
        const float ox = b2[e].x + acc[e].x;
        const float oy = b2[e].y + acc[e].y;
        float ss = ox * ox + oy * oy;
        ss += __shfl_xor(ss, 1);
        ss += __shfl_xor(ss, 2);
        ss += __shfl_xor(ss, 4);
        ss += __shfl_xor(ss, 8);
        ss += __shfl_xor(ss, 16);
        ss += __shfl_xor(ss, 32);
        const float scale = frcp(fmaxf(sqrtf(ss), 1e-12f));
        *reinterpret_cast<float2*>(&out[(es0 + e) * D_DIM + 2 * lane]) =
            make_float2(ox * scale, oy * scale);
    }
}

extern "C" void kernel_launch(void* const* d_in, const int* in_sizes, int n_in,
                              void* d_out, int out_size, void* d_ws, size_t ws_size,
                              hipStream_t stream)
{
    const int*   edge_index = (const int*)  d_in[0];   // [2,E]
    const float* edge_attr  = (const float*)d_in[1];   // [E,R]
    const int*   nbr        = (const int*)  d_in[2];   // [2,E,K]
    const float* emb        = (const float*)d_in[3];   // [N,D]
    const float* u          = (const float*)d_in[4];   // [N,R,U]
    const float* Wt         = (const float*)d_in[5];   // [R,U,A]
    const float* wt         = (const float*)d_in[6];   // [R,A]
    const float* Mt         = (const float*)d_in[7];   // [R,U,D]
    float*       out        = (float*)d_out;           // [2,E,D]

    gatne_fused<<<dim3(NBLOCKS), dim3(BLOCK), 0, stream>>>(
        edge_index, edge_attr, nbr, emb, u, Wt, wt, Mt, out);
}

// Round 9
// 643.373 us; speedup vs baseline: 1.8684x; 1.0776x over previous
//
#include <hip/hip_runtime.h>

// Problem constants (from reference)
#define E_EDGES 131072
#define K_NB    10
#define D_DIM   128
#define U_DIM   32
#define A_DIM   16
#define R_DIM   4

// Kernel tiling: 512-thread blocks — the allocator's no-spill regime
// (R8: VGPR=60, WRITE=output-only; 1024-thread blocks spill, R3/R4/R6).
#define EPG     4                    // edge-sides per wave pass
#define WAVES   8                    // waves per block (512 threads)
#define BLOCK   (WAVES * 64)
#define NGROUPS ((2 * E_EDGES) / EPG)   // 65536 wave-groups
#define NBLOCKS (NGROUPS / WAVES)       // 8192 blocks

// fast 1/x (v_rcp_f32, ~1e-7 rel err)
__device__ __forceinline__ float frcp(float x) { return __builtin_amdgcn_rcpf(x); }

// fast tanh via hardware exp2 (validated R3/R4/R6/R8: absmax 2^-10, passes)
__device__ __forceinline__ float fast_tanh(float x) {
    x = fminf(fmaxf(x, -10.f), 10.f);
    const float t = __expf(2.f * x);
    return (t - 1.f) * frcp(t + 1.f);
}

// R9: W back in REGISTERS (R1 scheme). R8 showed W-in-LDS floods the DS pipe
// (~512 ds_read_b32/pass in the score loop); DS-op count/pass ~930 * ~4cyc
// ~= the whole 552us. LDS now 20KB (ur+coef only); Wreg loaded after the
// gather phase (short lifetime) keeps peak VGPR ~100 < 128 cap.
__global__ __launch_bounds__(BLOCK, 4)
void gatne_fused(const int*   __restrict__ edge_index,  // [2,E]
                 const float* __restrict__ edge_attr,   // [E,R]
                 const int*   __restrict__ nbr,         // [2,E,K]
                 const float* __restrict__ emb,         // [N,D]
                 const float* __restrict__ u,           // [N,R,U] (=[N,128])
                 const float* __restrict__ Wt,          // [R,U,A]
                 const float* __restrict__ wt,          // [R,A]
                 const float* __restrict__ Mt,          // [R,U,D] (=[128,128])
                 float*       __restrict__ out)         // [2,E,D]
{
    __shared__ float ur_lds[WAVES][D_DIM];              // 4 KB  (per-wave u_r)
    __shared__ float coef_lds[WAVES][EPG][D_DIM];       // 16 KB (per-wave coef)

    const int tid  = threadIdx.x;
    const int wave = tid >> 6;
    const int lane = tid & 63;
    const int grp  = blockIdx.x * WAVES + wave;   // one group of EPG edge-sides
    const int es0  = grp * EPG;                   // first edge-side id
    const int side = es0 / E_EDGES;               // uniform within group
    const int i0   = es0 - side * E_EDGES;        // edge id of first

    // lane -> (r'=rl, a=al) mapping for the attention score phase
    const int rl = lane >> 4;
    const int al = lane & 15;

    const float wreg0 = wt[0 * A_DIM + al];
    const float wreg1 = wt[1 * A_DIM + al];
    const float wreg2 = wt[2 * A_DIM + al];
    const float wreg3 = wt[3 * A_DIM + al];

    // cooperative index / attr loads (broadcast later via shfl/readlane)
    int idxA = 0;
    if (lane < EPG * K_NB) idxA = nbr[es0 * K_NB + lane];          // 40 ints
    int entv = 0;
    if (lane < EPG)        entv = edge_index[es0 + lane];          // 4 ints
    float attrv = 0.f;
    if (lane < EPG * R_DIM) attrv = edge_attr[i0 * R_DIM + lane];  // 16 floats

    float* urp = ur_lds[wave];
    float* cfp = &coef_lds[wave][0][0];

    // ---------------- phase 1: ALL gathers up front (max MLP) ----------------
    float2 b2[EPG];
    float2 s[EPG];
    #pragma unroll
    for (int e = 0; e < EPG; ++e) {
        const int ent = __shfl(entv, e);
        b2[e] = *reinterpret_cast<const float2*>(&emb[ent * D_DIM + 2 * lane]);
        s[e] = make_float2(0.f, 0.f);
    }
    #pragma unroll
    for (int e = 0; e < EPG; ++e) {
        #pragma unroll
        for (int k = 0; k < K_NB; ++k) {
            const int node = __shfl(idxA, e * K_NB + k);   // uniform -> readlane
            const float2 v =
                *reinterpret_cast<const float2*>(&u[node * D_DIM + 2 * lane]);
            s[e].x += v.x; s[e].y += v.y;
        }
    }

    // this lane's W column from global (64KB table, L2-hot; once per pass).
    // Loaded AFTER gathers so its 32-reg lifetime doesn't overlap phase 1.
    float Wreg[U_DIM];
    #pragma unroll
    for (int uu = 0; uu < U_DIM; ++uu)
        Wreg[uu] = Wt[(rl * U_DIM + uu) * A_DIM + al];

    // ---------------- phase 2: per-edge attention + coef ----------------
    #pragma unroll
    for (int e = 0; e < EPG; ++e) {
        const float at0 = __shfl(attrv, e * 4 + 0);
        const float at1 = __shfl(attrv, e * 4 + 1);
        const float at2 = __shfl(attrv, e * 4 + 2);
        const float at3 = __shfl(attrv, e * 4 + 3);
        const float atm = (rl == 0) ? at0 : (rl == 1) ? at1 : (rl == 2) ? at2 : at3;

        *reinterpret_cast<float2*>(&urp[2 * lane]) =
            make_float2(s[e].x * 0.1f, s[e].y * 0.1f);   // mean over K=10
        // wave-private LDS: in-order DS pipe, single-wave producer/consumer.

        // w_r[al] = sum_r' attr[r'] * w[r',al]
        const float wr = at0 * wreg0 + at1 * wreg1 + at2 * wreg2 + at3 * wreg3;

        // scores: g[r] = sum_u u_r[r,u] * W[rl,u,al];  h[r,al] = sum_rl attr*g
        float sc[R_DIM];
        #pragma unroll
        for (int r = 0; r < R_DIM; ++r) {
            float g = 0.f;
            #pragma unroll
            for (int u4 = 0; u4 < U_DIM / 4; ++u4) {
                const float4 uv =
                    *reinterpret_cast<const float4*>(&urp[r * U_DIM + u4 * 4]);
                g += uv.x * Wreg[u4 * 4 + 0];
                g += uv.y * Wreg[u4 * 4 + 1];
                g += uv.z * Wreg[u4 * 4 + 2];
                g += uv.w * Wreg[u4 * 4 + 3];
            }
            float v0 = atm * g;
            v0 += __shfl_xor(v0, 16);           // reduce over r' groups
            v0 += __shfl_xor(v0, 32);
            float t = fast_tanh(v0) * wr;       // tanh(h[r,al]) * w_r[al]
            t += __shfl_xor(t, 1);              // reduce over a
            t += __shfl_xor(t, 2);
            t += __shfl_xor(t, 4);
            t += __shfl_xor(t, 8);
            sc[r] = t;                          // score[r], replicated all lanes
        }

        // softmax over R=4 (replicated per-lane, trivial)
        const float mx  = fmaxf(fmaxf(sc[0], sc[1]), fmaxf(sc[2], sc[3]));
        const float ex0 = __expf(sc[0] - mx), ex1 = __expf(sc[1] - mx);
        const float ex2 = __expf(sc[2] - mx), ex3 = __expf(sc[3] - mx);
        const float inv = frcp(ex0 + ex1 + ex2 + ex3);
        const float a0 = ex0 * inv, a1 = ex1 * inv, a2 = ex2 * inv, a3 = ex3 * inv;

        // coef[ru] = attr[r] * v[u], v[u] = sum_r att[r]*u_r[r,u]
        const int ub = (2 * lane) & 31;
        const float vA = a0 * urp[0 * U_DIM + ub]     + a1 * urp[1 * U_DIM + ub] +
                         a2 * urp[2 * U_DIM + ub]     + a3 * urp[3 * U_DIM + ub];
        const float vB = a0 * urp[0 * U_DIM + ub + 1] + a1 * urp[1 * U_DIM + ub + 1] +
                         a2 * urp[2 * U_DIM + ub + 1] + a3 * urp[3 * U_DIM + ub + 1];
        *reinterpret_cast<float2*>(&cfp[e * D_DIM + 2 * lane]) =
            make_float2(atm * vA, atm * vB);
    }

    // ------- joint matvec: out_d = sum_ru coef[ru] * M[ru,d], M from L2 ------
    // R6 lesson: uncontrolled global-M loop -> load batching -> spill.
    // #pragma unroll 1 + manual A/B prefetch with STATIC names (rule #20).
    float2 acc[EPG];
    #pragma unroll
    for (int e = 0; e < EPG; ++e) { acc[e].x = 0.f; acc[e].y = 0.f; }

    const float2* mp = reinterpret_cast<const float2*>(&Mt[2 * lane]);
    float2 mA0, mA1, mA2, mA3, mB0, mB1, mB2, mB3;
    mA0 = mp[0 * 64]; mA1 = mp[1 * 64]; mA2 = mp[2 * 64]; mA3 = mp[3 * 64];

    #pragma unroll 1
    for (int c = 0; c < 32; c += 2) {
        // prefetch chunk c+1 into B while computing c from A
        {
            const float2* q = mp + (c + 1) * 4 * 64;
            mB0 = q[0 * 64]; mB1 = q[1 * 64]; mB2 = q[2 * 64]; mB3 = q[3 * 64];
        }
        {
            float4 cf4[EPG];
            #pragma unroll
            for (int e = 0; e < EPG; ++e)
                cf4[e] = *reinterpret_cast<const float4*>(&cfp[e * D_DIM + c * 4]);
            #pragma unroll
            for (int e = 0; e < EPG; ++e) {
                acc[e].x += cf4[e].x * mA0.x; acc[e].y += cf4[e].x * mA0.y;
                acc[e].x += cf4[e].y * mA1.x; acc[e].y += cf4[e].y * mA1.y;
                acc[e].x += cf4[e].z * mA2.x; acc[e].y += cf4[e].z * mA2.y;
                acc[e].x += cf4[e].w * mA3.x; acc[e].y += cf4[e].w * mA3.y;
            }
        }
        // prefetch chunk c+2 into A while computing c+1 from B
        if (c + 2 < 32) {
            const float2* q = mp + (c + 2) * 4 * 64;
            mA0 = q[0 * 64]; mA1 = q[1 * 64]; mA2 = q[2 * 64]; mA3 = q[3 * 64];
        }
        {
            float4 cf4[EPG];
            #pragma unroll
            for (int e = 0; e < EPG; ++e)
                cf4[e] = *reinterpret_cast<const float4*>(&cfp[e * D_DIM + (c + 1) * 4]);
            #pragma unroll
            for (int e = 0; e < EPG; ++e) {
                acc[e].x += cf4[e].x * mB0.x; acc[e].y += cf4[e].x * mB0.y;
                acc[e].x += cf4[e].y * mB1.x; acc[e].y += cf4[e].y * mB1.y;
                acc[e].x += cf4[e].z * mB2.x; acc[e].y += cf4[e].z * mB2.y;
                acc[e].x += cf4[e].w * mB3.x; acc[e].y += cf4[e].w * mB3.y;
            }
        }
    }

    // ---------------- epilogue: + emb, L2 normalize, store -------------------
    #pragma unroll
    for (int e = 0; e < EPG; ++e) {
        const float ox = b2[e].x + acc[e].x;
        const float oy = b2[e].y + acc[e].y;
        float ss = ox * ox + oy * oy;
        ss += __shfl_xor(ss, 1);
        ss += __shfl_xor(ss, 2);
        ss += __shfl_xor(ss, 4);
        ss += __shfl_xor(ss, 8);
        ss += __shfl_xor(ss, 16);
        ss += __shfl_xor(ss, 32);
        const float scale = frcp(fmaxf(sqrtf(ss), 1e-12f));
        *reinterpret_cast<float2*>(&out[(es0 + e) * D_DIM + 2 * lane]) =
            make_float2(ox * scale, oy * scale);
    }
}

extern "C" void kernel_launch(void* const* d_in, const int* in_sizes, int n_in,
                              void* d_out, int out_size, void* d_ws, size_t ws_size,
                              hipStream_t stream)
{
    const int*   edge_index = (const int*)  d_in[0];   // [2,E]
    const float* edge_attr  = (const float*)d_in[1];   // [E,R]
    const int*   nbr        = (const int*)  d_in[2];   // [2,E,K]
    const float* emb        = (const float*)d_in[3];   // [N,D]
    const float* u          = (const float*)d_in[4];   // [N,R,U]
    const float* Wt         = (const float*)d_in[5];   // [R,U,A]
    const float* wt         = (const float*)d_in[6];   // [R,A]
    const float* Mt         = (const float*)d_in[7];   // [R,U,D]
    float*       out        = (float*)d_out;           // [2,E,D]

    gatne_fused<<<dim3(NBLOCKS), dim3(BLOCK), 0, stream>>>(
        edge_index, edge_attr, nbr, emb, u, Wt, wt, Mt, out);
}

// Round 10
// 642.307 us; speedup vs baseline: 1.8715x; 1.0017x over previous
//
#include <hip/hip_runtime.h>

// Problem constants (from reference)
#define E_EDGES 131072
#define K_NB    10
#define D_DIM   128
#define U_DIM   32
#define A_DIM   16
#define R_DIM   4

// Kernel tiling: 512-thread blocks — the allocator's no-spill regime
// (R8/R9: VGPR=60-64, WRITE~output-only; 1024-thread blocks spill, R3/R4/R6).
#define EPG     4                    // edge-sides per wave pass
#define WAVES   8                    // waves per block (512 threads)
#define BLOCK   (WAVES * 64)
#define NGROUPS ((2 * E_EDGES) / EPG)   // 65536 wave-groups
#define NBLOCKS (NGROUPS / WAVES)       // 8192 blocks

// fast 1/x (v_rcp_f32, ~1e-7 rel err)
__device__ __forceinline__ float frcp(float x) { return __builtin_amdgcn_rcpf(x); }

// fast tanh via hardware exp2 (validated R3-R9: absmax 2^-10, passes)
__device__ __forceinline__ float fast_tanh(float x) {
    x = fminf(fmaxf(x, -10.f), 10.f);
    const float t = __expf(2.f * x);
    return (t - 1.f) * frcp(t + 1.f);
}

// R10: per-edge u_r LDS slots. R9's four edges shared ONE urp buffer ->
// edge e+1's ds_write had to wait for edge e's last read -> 4 serialized
// ~1.5k-cycle chains per pass. Separate slots make the 4 score/softmax/coef
// chains independent (4-way ILP in-wave). emb gather moved to epilogue to
// cut mid-kernel live regs (kills R9's residual 13MB spill).
__global__ __launch_bounds__(BLOCK, 4)
void gatne_fused(const int*   __restrict__ edge_index,  // [2,E]
                 const float* __restrict__ edge_attr,   // [E,R]
                 const int*   __restrict__ nbr,         // [2,E,K]
                 const float* __restrict__ emb,         // [N,D]
                 const float* __restrict__ u,           // [N,R,U] (=[N,128])
                 const float* __restrict__ Wt,          // [R,U,A]
                 const float* __restrict__ wt,          // [R,A]
                 const float* __restrict__ Mt,          // [R,U,D] (=[128,128])
                 float*       __restrict__ out)         // [2,E,D]
{
    __shared__ float ur_lds[WAVES][EPG][D_DIM];         // 16 KB (per-wave,per-edge u_r)
    __shared__ float coef_lds[WAVES][EPG][D_DIM];       // 16 KB (per-wave coef)

    const int tid  = threadIdx.x;
    const int wave = tid >> 6;
    const int lane = tid & 63;
    const int grp  = blockIdx.x * WAVES + wave;   // one group of EPG edge-sides
    const int es0  = grp * EPG;                   // first edge-side id
    const int side = es0 / E_EDGES;               // uniform within group
    const int i0   = es0 - side * E_EDGES;        // edge id of first

    // lane -> (r'=rl, a=al) mapping for the attention score phase
    const int rl = lane >> 4;
    const int al = lane & 15;

    const float wreg0 = wt[0 * A_DIM + al];
    const float wreg1 = wt[1 * A_DIM + al];
    const float wreg2 = wt[2 * A_DIM + al];
    const float wreg3 = wt[3 * A_DIM + al];

    // cooperative index / attr loads (broadcast later via shfl/readlane)
    int idxA = 0;
    if (lane < EPG * K_NB) idxA = nbr[es0 * K_NB + lane];          // 40 ints
    int entv = 0;
    if (lane < EPG)        entv = edge_index[es0 + lane];          // 4 ints
    float attrv = 0.f;
    if (lane < EPG * R_DIM) attrv = edge_attr[i0 * R_DIM + lane];  // 16 floats

    float* cfp = &coef_lds[wave][0][0];

    // ---------------- phase 1: u-row gathers (max MLP) ----------------
    float2 s[EPG];
    #pragma unroll
    for (int e = 0; e < EPG; ++e) s[e] = make_float2(0.f, 0.f);
    #pragma unroll
    for (int k = 0; k < K_NB; ++k) {
        #pragma unroll
        for (int e = 0; e < EPG; ++e) {
            const int node = __shfl(idxA, e * K_NB + k);   // uniform -> readlane
            const float2 v =
                *reinterpret_cast<const float2*>(&u[node * D_DIM + 2 * lane]);
            s[e].x += v.x; s[e].y += v.y;
        }
    }

    // publish all four u_r rows, freeing s[e] registers early.
    // wave-private LDS: in-order DS pipe, single-wave producer/consumer.
    #pragma unroll
    for (int e = 0; e < EPG; ++e)
        *reinterpret_cast<float2*>(&ur_lds[wave][e][2 * lane]) =
            make_float2(s[e].x * 0.1f, s[e].y * 0.1f);   // mean over K=10

    // this lane's W column from global (64KB table, L2-hot; once per pass).
    float Wreg[U_DIM];
    #pragma unroll
    for (int uu = 0; uu < U_DIM; ++uu)
        Wreg[uu] = Wt[(rl * U_DIM + uu) * A_DIM + al];

    // ---------------- phase 2: per-edge attention + coef (4 independent) ----
    #pragma unroll
    for (int e = 0; e < EPG; ++e) {
        const float* urp = &ur_lds[wave][e][0];
        const float at0 = __shfl(attrv, e * 4 + 0);
        const float at1 = __shfl(attrv, e * 4 + 1);
        const float at2 = __shfl(attrv, e * 4 + 2);
        const float at3 = __shfl(attrv, e * 4 + 3);
        const float atm = (rl == 0) ? at0 : (rl == 1) ? at1 : (rl == 2) ? at2 : at3;

        // w_r[al] = sum_r' attr[r'] * w[r',al]
        const float wr = at0 * wreg0 + at1 * wreg1 + at2 * wreg2 + at3 * wreg3;

        // scores: g[r] = sum_u u_r[r,u] * W[rl,u,al];  h[r,al] = sum_rl attr*g
        float sc[R_DIM];
        #pragma unroll
        for (int r = 0; r < R_DIM; ++r) {
            float g = 0.f;
            #pragma unroll
            for (int u4 = 0; u4 < U_DIM / 4; ++u4) {
                const float4 uv =
                    *reinterpret_cast<const float4*>(&urp[r * U_DIM + u4 * 4]);
                g += uv.x * Wreg[u4 * 4 + 0];
                g += uv.y * Wreg[u4 * 4 + 1];
                g += uv.z * Wreg[u4 * 4 + 2];
                g += uv.w * Wreg[u4 * 4 + 3];
            }
            float v0 = atm * g;
            v0 += __shfl_xor(v0, 16);           // reduce over r' groups
            v0 += __shfl_xor(v0, 32);
            float t = fast_tanh(v0) * wr;       // tanh(h[r,al]) * w_r[al]
            t += __shfl_xor(t, 1);              // reduce over a
            t += __shfl_xor(t, 2);
            t += __shfl_xor(t, 4);
            t += __shfl_xor(t, 8);
            sc[r] = t;                          // score[r], replicated all lanes
        }

        // softmax over R=4 (replicated per-lane, trivial)
        const float mx  = fmaxf(fmaxf(sc[0], sc[1]), fmaxf(sc[2], sc[3]));
        const float ex0 = __expf(sc[0] - mx), ex1 = __expf(sc[1] - mx);
        const float ex2 = __expf(sc[2] - mx), ex3 = __expf(sc[3] - mx);
        const float inv = frcp(ex0 + ex1 + ex2 + ex3);
        const float a0 = ex0 * inv, a1 = ex1 * inv, a2 = ex2 * inv, a3 = ex3 * inv;

        // coef[ru] = attr[r] * v[u], v[u] = sum_r att[r]*u_r[r,u]
        const int ub = (2 * lane) & 31;
        const float vA = a0 * urp[0 * U_DIM + ub]     + a1 * urp[1 * U_DIM + ub] +
                         a2 * urp[2 * U_DIM + ub]     + a3 * urp[3 * U_DIM + ub];
        const float vB = a0 * urp[0 * U_DIM + ub + 1] + a1 * urp[1 * U_DIM + ub + 1] +
                         a2 * urp[2 * U_DIM + ub + 1] + a3 * urp[3 * U_DIM + ub + 1];
        *reinterpret_cast<float2*>(&cfp[e * D_DIM + 2 * lane]) =
            make_float2(atm * vA, atm * vB);
    }

    // ------- joint matvec: out_d = sum_ru coef[ru] * M[ru,d], M from L2 ------
    // R6 lesson: uncontrolled global-M loop -> load batching -> spill.
    // #pragma unroll 1 + manual A/B prefetch with STATIC names (rule #20).
    float2 acc[EPG];
    #pragma unroll
    for (int e = 0; e < EPG; ++e) { acc[e].x = 0.f; acc[e].y = 0.f; }

    const float2* mp = reinterpret_cast<const float2*>(&Mt[2 * lane]);
    float2 mA0, mA1, mA2, mA3, mB0, mB1, mB2, mB3;
    mA0 = mp[0 * 64]; mA1 = mp[1 * 64]; mA2 = mp[2 * 64]; mA3 = mp[3 * 64];

    #pragma unroll 1
    for (int c = 0; c < 32; c += 2) {
        // prefetch chunk c+1 into B while computing c from A
        {
            const float2* q = mp + (c + 1) * 4 * 64;
            mB0 = q[0 * 64]; mB1 = q[1 * 64]; mB2 = q[2 * 64]; mB3 = q[3 * 64];
        }
        {
            float4 cf4[EPG];
            #pragma unroll
            for (int e = 0; e < EPG; ++e)
                cf4[e] = *reinterpret_cast<const float4*>(&cfp[e * D_DIM + c * 4]);
            #pragma unroll
            for (int e = 0; e < EPG; ++e) {
                acc[e].x += cf4[e].x * mA0.x; acc[e].y += cf4[e].x * mA0.y;
                acc[e].x += cf4[e].y * mA1.x; acc[e].y += cf4[e].y * mA1.y;
                acc[e].x += cf4[e].z * mA2.x; acc[e].y += cf4[e].z * mA2.y;
                acc[e].x += cf4[e].w * mA3.x; acc[e].y += cf4[e].w * mA3.y;
            }
        }
        // prefetch chunk c+2 into A while computing c+1 from B
        if (c + 2 < 32) {
            const float2* q = mp + (c + 2) * 4 * 64;
            mA0 = q[0 * 64]; mA1 = q[1 * 64]; mA2 = q[2 * 64]; mA3 = q[3 * 64];
        }
        {
            float4 cf4[EPG];
            #pragma unroll
            for (int e = 0; e < EPG; ++e)
                cf4[e] = *reinterpret_cast<const float4*>(&cfp[e * D_DIM + (c + 1) * 4]);
            #pragma unroll
            for (int e = 0; e < EPG; ++e) {
                acc[e].x += cf4[e].x * mB0.x; acc[e].y += cf4[e].x * mB0.y;
                acc[e].x += cf4[e].y * mB1.x; acc[e].y += cf4[e].y * mB1.y;
                acc[e].x += cf4[e].z * mB2.x; acc[e].y += cf4[e].z * mB2.y;
                acc[e].x += cf4[e].w * mB3.x; acc[e].y += cf4[e].w * mB3.y;
            }
        }
    }

    // ---------- epilogue: emb gather here (short b2 lifetime), L2 norm -------
    #pragma unroll
    for (int e = 0; e < EPG; ++e) {
        const int ent = __shfl(entv, e);
        const float2 b2 =
            *reinterpret_cast<const float2*>(&emb[ent * D_DIM + 2 * lane]);
        const float ox = b2.x + acc[e].x;
        const float oy = b2.y + acc[e].y;
        float ss = ox * ox + oy * oy;
        ss += __shfl_xor(ss, 1);
        ss += __shfl_xor(ss, 2);
        ss += __shfl_xor(ss, 4);
        ss += __shfl_xor(ss, 8);
        ss += __shfl_xor(ss, 16);
        ss += __shfl_xor(ss, 32);
        const float scale = frcp(fmaxf(sqrtf(ss), 1e-12f));
        *reinterpret_cast<float2*>(&out[(es0 + e) * D_DIM + 2 * lane]) =
            make_float2(ox * scale, oy * scale);
    }
}

extern "C" void kernel_launch(void* const* d_in, const int* in_sizes, int n_in,
                              void* d_out, int out_size, void* d_ws, size_t ws_size,
                              hipStream_t stream)
{
    const int*   edge_index = (const int*)  d_in[0];   // [2,E]
    const float* edge_attr  = (const float*)d_in[1];   // [E,R]
    const int*   nbr        = (const int*)  d_in[2];   // [2,E,K]
    const float* emb        = (const float*)d_in[3];   // [N,D]
    const float* u          = (const float*)d_in[4];   // [N,R,U]
    const float* Wt         = (const float*)d_in[5];   // [R,U,A]
    const float* wt         = (const float*)d_in[6];   // [R,A]
    const float* Mt         = (const float*)d_in[7];   // [R,U,D]
    float*       out        = (float*)d_out;           // [2,E,D]

    gatne_fused<<<dim3(NBLOCKS), dim3(BLOCK), 0, stream>>>(
        edge_index, edge_attr, nbr, emb, u, Wt, wt, Mt, out);
}